// Round 1
// baseline (328.437 us; speedup 1.0000x reference)
//
#include <hip/hip_runtime.h>
#include <math.h>

// Problem constants: B=2, N=512, DIM=512, HEADS=8, DIM_HEAD=64
// out[beta,eta,mu,z] = DFT3(S_k*v)[beta,eta,mu,z] / DFT3(k_)[beta,eta,mu,z]
// DFT3 over (b=2, h=8, m=512 zero-padded to 1024), mu in [0,512).

#define NROW 1024   // B*N rows of the GEMM
#define DIMX 512
#define NPOS 512
#define NBE  16     // 2*8 (b,h) DFT bins

__global__ void zero_init_kernel(double* sumsq) { *sumsq = 0.0; }

__global__ __launch_bounds__(256)
void gemm_kv_kernel(const float* __restrict__ x,
                    const float* __restrict__ Wk,
                    const float* __restrict__ Wv,
                    float* __restrict__ K,
                    float* __restrict__ V,
                    double* __restrict__ sumsq)
{
    const int r0 = blockIdx.x * 8;     // 8 rows per block
    const int t  = threadIdx.x;        // 0..255; cols t and t+256
    __shared__ float xs[8][64];
    __shared__ float red[4];
    float accK0[8] = {0,0,0,0,0,0,0,0};
    float accK1[8] = {0,0,0,0,0,0,0,0};
    float accV0[8] = {0,0,0,0,0,0,0,0};
    float accV1[8] = {0,0,0,0,0,0,0,0};

    for (int kb = 0; kb < DIMX; kb += 64) {
        __syncthreads();
        for (int e = t; e < 512; e += 256)
            xs[e >> 6][e & 63] = x[(size_t)(r0 + (e >> 6)) * DIMX + kb + (e & 63)];
        __syncthreads();
        for (int kk2 = 0; kk2 < 64; ++kk2) {
            const int k = kb + kk2;
            const float wk0 = Wk[(size_t)k * DIMX + t];
            const float wk1 = Wk[(size_t)k * DIMX + t + 256];
            const float wv0 = Wv[(size_t)k * DIMX + t];
            const float wv1 = Wv[(size_t)k * DIMX + t + 256];
            #pragma unroll
            for (int i = 0; i < 8; ++i) {
                const float xv = xs[i][kk2];
                accK0[i] = fmaf(xv, wk0, accK0[i]);
                accK1[i] = fmaf(xv, wk1, accK1[i]);
                accV0[i] = fmaf(xv, wv0, accV0[i]);
                accV1[i] = fmaf(xv, wv1, accV1[i]);
            }
        }
    }

    float ss = 0.f;
    #pragma unroll
    for (int i = 0; i < 8; ++i) {
        K[(size_t)(r0 + i) * DIMX + t]       = accK0[i];
        K[(size_t)(r0 + i) * DIMX + t + 256] = accK1[i];
        V[(size_t)(r0 + i) * DIMX + t]       = accV0[i];
        V[(size_t)(r0 + i) * DIMX + t + 256] = accV1[i];
        ss += accK0[i]*accK0[i] + accK1[i]*accK1[i];
        ss += accV0[i]*0.f;  // keep V in regs, no-op
    }
    #pragma unroll
    for (int off = 32; off > 0; off >>= 1)
        ss += __shfl_down(ss, off, 64);
    if ((t & 63) == 0) red[t >> 6] = ss;
    __syncthreads();
    if (t == 0) {
        double tot = (double)red[0] + (double)red[1] + (double)red[2] + (double)red[3];
        atomicAdd(sumsq, tot);
    }
}

// 8-point DFT twiddles: exp(-2*pi*i*k/8)
__device__ __constant__ float C8[8] = {
    1.f, 0.70710678118654752440f, 0.f, -0.70710678118654752440f,
   -1.f, -0.70710678118654752440f, 0.f, 0.70710678118654752440f };
__device__ __constant__ float S8[8] = {
    0.f, -0.70710678118654752440f, -1.f, -0.70710678118654752440f,
    0.f,  0.70710678118654752440f,  1.f,  0.70710678118654752440f };

// Per position m: elu(K/norm), S_k, P = S_k*V, then the 2x8 (b,h)-DFT.
// Gk/Gp layout: [be=beta*8+eta][m][z] as float2 (complex).
__global__ __launch_bounds__(256)
void stage1_kernel(const float* __restrict__ K,
                   const float* __restrict__ V,
                   const double* __restrict__ sumsq,
                   float2* __restrict__ Gk,
                   float2* __restrict__ Gp)
{
    const int m = blockIdx.x;     // 0..511
    const int t = threadIdx.x;    // 0..255
    __shared__ float kk[2][8][64];
    __shared__ float pp[2][8][64];
    __shared__ float sk[2][8];

    const float scale = (float)(1.0 / sqrt(*sumsq));

    for (int e = t; e < 1024; e += 256) {
        const int b = e >> 9, rem = e & 511, h = rem >> 6, z = rem & 63;
        const size_t src = (size_t)(b * 512 + m) * DIMX + h * 64 + z;
        const float kv = K[src] * scale;
        kk[b][h][z] = kv > 0.f ? kv : expm1f(kv);   // jax.nn.elu uses expm1
        pp[b][h][z] = V[src];
    }
    __syncthreads();
    if (t < 16) {
        const int b = t >> 3, h = t & 7;
        float s = 0.f;
        #pragma unroll
        for (int z = 0; z < 64; ++z) s += kk[b][h][z];
        sk[b][h] = s;
    }
    __syncthreads();
    for (int e = t; e < 1024; e += 256) {
        const int b = e >> 9, rem = e & 511, h = rem >> 6, z = rem & 63;
        pp[b][h][z] *= sk[b][h];
    }
    __syncthreads();
    for (int e = t; e < 1024; e += 256) {
        const int be = e >> 6;            // beta*8+eta
        const int z  = e & 63;
        const int beta = be >> 3, eta = be & 7;
        float gkr = 0.f, gki = 0.f, gpr = 0.f, gpi = 0.f;
        #pragma unroll
        for (int b = 0; b < 2; ++b) {
            const float sgn = (beta & b) ? -1.f : 1.f;
            #pragma unroll
            for (int h = 0; h < 8; ++h) {
                const int ph = (eta * h) & 7;
                const float cr = C8[ph], ci = S8[ph];
                const float a = kk[b][h][z] * sgn;
                gkr = fmaf(a, cr, gkr); gki = fmaf(a, ci, gki);
                const float p = pp[b][h][z] * sgn;
                gpr = fmaf(p, cr, gpr); gpi = fmaf(p, ci, gpi);
            }
        }
        const size_t o = ((size_t)be * NPOS + m) * 64 + z;
        Gk[o] = make_float2(gkr, gki);
        Gp[o] = make_float2(gpr, gpi);
    }
}

// m-DFT (512 in -> mu in [0,512), twiddle base 1024) + complex divide.
// One block per (be, z). Threads each handle mu = t and t+256.
__global__ __launch_bounds__(256)
void mdft_kernel(const float2* __restrict__ Gk,
                 const float2* __restrict__ Gp,
                 float* __restrict__ out,
                 int out_cplx)
{
    const int blk = blockIdx.x;         // 0..1023
    const int be = blk >> 6, z = blk & 63;
    const int t = threadIdx.x;
    __shared__ float2 gk[512];
    __shared__ float2 gp[512];
    __shared__ float2 w[1024];

    for (int m = t; m < 512; m += 256) {
        const size_t idx = ((size_t)be * NPOS + m) * 64 + z;
        gk[m] = Gk[idx];
        gp[m] = Gp[idx];
    }
    for (int j = t; j < 1024; j += 256) {
        double s, c;
        sincos(-6.2831853071795864769 * (double)j / 1024.0, &s, &c);
        w[j] = make_float2((float)c, (float)s);
    }
    __syncthreads();

    #pragma unroll
    for (int half = 0; half < 2; ++half) {
        const int mu = t + half * 256;
        double dr = 0.0, di = 0.0, nr = 0.0, ni = 0.0;
        int idx = 0;                    // (mu*m) mod 1024, incremental
        for (int m = 0; m < 512; ++m) {
            const float2 tw = w[idx];
            idx = (idx + mu) & 1023;
            const float2 a = gk[m];
            dr += (double)(a.x * tw.x - a.y * tw.y);
            di += (double)(a.x * tw.y + a.y * tw.x);
            const float2 p = gp[m];
            nr += (double)(p.x * tw.x - p.y * tw.y);
            ni += (double)(p.x * tw.y + p.y * tw.x);
        }
        const double dmag = dr * dr + di * di;
        const double orr = (nr * dr + ni * di) / dmag;
        const double oii = (ni * dr - nr * di) / dmag;
        const size_t o = ((size_t)be * NPOS + mu) * 64 + z;
        if (out_cplx) {
            out[2 * o]     = (float)orr;
            out[2 * o + 1] = (float)oii;
        } else {
            out[o] = (float)orr;
        }
    }
}

extern "C" void kernel_launch(void* const* d_in, const int* in_sizes, int n_in,
                              void* d_out, int out_size, void* d_ws, size_t ws_size,
                              hipStream_t stream)
{
    // setup_inputs order: x, Wq, Wk, Wv, Er — only x, Wk, Wv are needed
    const float* x  = (const float*)d_in[0];
    const float* Wk = (const float*)d_in[2];
    const float* Wv = (const float*)d_in[3];
    float* out = (float*)d_out;

    char* ws = (char*)d_ws;
    float*  K   = (float*)(ws);                           // 2 MB
    float*  V   = (float*)(ws + (size_t)2097152);         // 2 MB
    float2* Gk  = (float2*)(ws + (size_t)4194304);        // 4 MB
    double* ssq = (double*)(ws + (size_t)8388608);        // 8 B
    const int out_cplx = (out_size >= 2 * 2 * 8 * 512 * 64) ? 1 : 0;

    float2* Gp;
    if (ws_size >= (size_t)8388672 + (size_t)4194304) {
        Gp = (float2*)(ws + (size_t)8388672);             // 4 MB
    } else {
        // Fallback: alias Gp with d_out (safe: each mdft block stages its
        // (be,z) slice into LDS before writing the same slice back).
        Gp = (float2*)d_out;
    }

    hipLaunchKernelGGL(zero_init_kernel, dim3(1), dim3(1), 0, stream, ssq);
    hipLaunchKernelGGL(gemm_kv_kernel, dim3(128), dim3(256), 0, stream,
                       x, Wk, Wv, K, V, ssq);
    hipLaunchKernelGGL(stage1_kernel, dim3(512), dim3(256), 0, stream,
                       K, V, ssq, Gk, Gp);
    hipLaunchKernelGGL(mdft_kernel, dim3(1024), dim3(256), 0, stream,
                       Gk, Gp, out, out_cplx);
}

// Round 2
// 192.076 us; speedup vs baseline: 1.7099x; 1.7099x over previous
//
#include <hip/hip_runtime.h>
#include <math.h>

// Problem constants: B=2, N=512, DIM=512, HEADS=8, DIM_HEAD=64
// out[beta,eta,mu,z] = DFT3(S_k*v)[beta,eta,mu,z] / DFT3(k_)[beta,eta,mu,z]
// DFT3 over (b=2, h=8, m=512 zero-padded to 1024), mu in [0,512).

#define DIMX 512
#define NPOS 512

// Fused K/V GEMM. grid 256: sel = blk>>7 (0 -> K, 1 -> V), 8 rows per block.
// Each thread: cols t and t+256, 8 row-accumulators each.
__global__ __launch_bounds__(256)
void gemm_kv_kernel(const float* __restrict__ x,
                    const float* __restrict__ Wk,
                    const float* __restrict__ Wv,
                    float* __restrict__ K,
                    float* __restrict__ V,
                    double* __restrict__ sumsq)
{
    const int sel = blockIdx.x >> 7;
    const int r0  = (blockIdx.x & 127) * 8;
    const int t   = threadIdx.x;
    const float* __restrict__ W   = sel ? Wv : Wk;
    float* __restrict__       Out = sel ? V  : K;

    __shared__ float xs[8][DIMX];   // 16 KB
    __shared__ float red[4];

    for (int e = t; e < 8 * DIMX; e += 256)
        xs[e >> 9][e & 511] = x[(size_t)(r0 + (e >> 9)) * DIMX + (e & 511)];
    __syncthreads();

    float acc0[8] = {0,0,0,0,0,0,0,0};
    float acc1[8] = {0,0,0,0,0,0,0,0};

    for (int k = 0; k < DIMX; k += 4) {
        float w0[4], w1[4];
        #pragma unroll
        for (int j = 0; j < 4; ++j) {
            w0[j] = W[(size_t)(k + j) * DIMX + t];
            w1[j] = W[(size_t)(k + j) * DIMX + t + 256];
        }
        #pragma unroll
        for (int i = 0; i < 8; ++i) {
            const float4 xv = *(const float4*)&xs[i][k];
            acc0[i] = fmaf(xv.x, w0[0], acc0[i]);
            acc0[i] = fmaf(xv.y, w0[1], acc0[i]);
            acc0[i] = fmaf(xv.z, w0[2], acc0[i]);
            acc0[i] = fmaf(xv.w, w0[3], acc0[i]);
            acc1[i] = fmaf(xv.x, w1[0], acc1[i]);
            acc1[i] = fmaf(xv.y, w1[1], acc1[i]);
            acc1[i] = fmaf(xv.z, w1[2], acc1[i]);
            acc1[i] = fmaf(xv.w, w1[3], acc1[i]);
        }
    }

    float ss = 0.f;
    #pragma unroll
    for (int i = 0; i < 8; ++i) {
        Out[(size_t)(r0 + i) * DIMX + t]       = acc0[i];
        Out[(size_t)(r0 + i) * DIMX + t + 256] = acc1[i];
        ss += acc0[i] * acc0[i] + acc1[i] * acc1[i];
    }
    if (sel == 0) {   // Frobenius sumsq of K only
        #pragma unroll
        for (int off = 32; off > 0; off >>= 1)
            ss += __shfl_down(ss, off, 64);
        if ((t & 63) == 0) red[t >> 6] = ss;
        __syncthreads();
        if (t == 0) {
            double tot = (double)red[0] + (double)red[1] + (double)red[2] + (double)red[3];
            atomicAdd(sumsq, tot);
        }
    }
}

// 8-point DFT twiddles: exp(-2*pi*i*k/8)
__device__ __constant__ float C8[8] = {
    1.f, 0.70710678118654752440f, 0.f, -0.70710678118654752440f,
   -1.f, -0.70710678118654752440f, 0.f, 0.70710678118654752440f };
__device__ __constant__ float S8[8] = {
    0.f, -0.70710678118654752440f, -1.f, -0.70710678118654752440f,
    0.f,  0.70710678118654752440f,  1.f,  0.70710678118654752440f };

// Per position m: elu(K/norm), S_k, P = S_k*V, then the 2x8 (b,h)-DFT.
// Gk/Gp layout: [be=beta*8+eta][m][z] as float2 (complex).
__global__ __launch_bounds__(256)
void stage1_kernel(const float* __restrict__ K,
                   const float* __restrict__ V,
                   const double* __restrict__ sumsq,
                   float2* __restrict__ Gk,
                   float2* __restrict__ Gp)
{
    const int m = blockIdx.x;     // 0..511
    const int t = threadIdx.x;    // 0..255
    __shared__ float kk[2][8][64];
    __shared__ float pp[2][8][64];
    __shared__ float sk[2][8];

    const float scale = (float)(1.0 / sqrt(*sumsq));

    for (int e = t; e < 1024; e += 256) {
        const int b = e >> 9, rem = e & 511, h = rem >> 6, z = rem & 63;
        const size_t src = (size_t)(b * 512 + m) * DIMX + h * 64 + z;
        const float kv = K[src] * scale;
        kk[b][h][z] = kv > 0.f ? kv : expm1f(kv);   // jax.nn.elu uses expm1
        pp[b][h][z] = V[src];
    }
    __syncthreads();
    if (t < 16) {
        const int b = t >> 3, h = t & 7;
        float s = 0.f;
        #pragma unroll
        for (int z = 0; z < 64; ++z) s += kk[b][h][z];
        sk[b][h] = s;
    }
    __syncthreads();
    for (int e = t; e < 1024; e += 256) {
        const int b = e >> 9, rem = e & 511, h = rem >> 6, z = rem & 63;
        pp[b][h][z] *= sk[b][h];
    }
    __syncthreads();
    for (int e = t; e < 1024; e += 256) {
        const int be = e >> 6;            // beta*8+eta
        const int z  = e & 63;
        const int beta = be >> 3, eta = be & 7;
        float gkr = 0.f, gki = 0.f, gpr = 0.f, gpi = 0.f;
        #pragma unroll
        for (int b = 0; b < 2; ++b) {
            const float sgn = (beta & b) ? -1.f : 1.f;
            #pragma unroll
            for (int h = 0; h < 8; ++h) {
                const int ph = (eta * h) & 7;
                const float cr = C8[ph], ci = S8[ph];
                const float a = kk[b][h][z] * sgn;
                gkr = fmaf(a, cr, gkr); gki = fmaf(a, ci, gki);
                const float p = pp[b][h][z] * sgn;
                gpr = fmaf(p, cr, gpr); gpi = fmaf(p, ci, gpi);
            }
        }
        const size_t o = ((size_t)be * NPOS + m) * 64 + z;
        Gk[o] = make_float2(gkr, gki);
        Gp[o] = make_float2(gpr, gpi);
    }
}

// m-DFT v2: fp32 accumulation, register twiddle recurrence (no LDS twiddle
// table -> no bank conflicts). grid 512: blk = be(16)*32 + zg(16)*2 + half(2).
// Each block: (be, z = zg*4..zg*4+3, mu = half*256 + t). 4 z per thread.
__global__ __launch_bounds__(256)
void mdft_v2_kernel(const float2* __restrict__ Gk,
                    const float2* __restrict__ Gp,
                    float* __restrict__ out,
                    int out_cplx)
{
    const int blk  = blockIdx.x;
    const int be   = blk >> 5;
    const int zg   = (blk >> 1) & 15;
    const int half = blk & 1;
    const int t    = threadIdx.x;
    const int mu   = half * 256 + t;

    __shared__ float2 gk[NPOS][4];   // 16 KB
    __shared__ float2 gp[NPOS][4];   // 16 KB

    for (int e = t; e < NPOS * 4; e += 256) {
        const int m = e >> 2, z = e & 3;
        const size_t idx = ((size_t)be * NPOS + m) * 64 + zg * 4 + z;
        gk[m][z] = Gk[idx];
        gp[m][z] = Gp[idx];
    }
    __syncthreads();

    const float C = -6.2831853071795864769f / 1024.0f;
    // ws = exp(-2*pi*i*mu/1024), ws16 = exp(-2*pi*i*((16*mu) mod 1024)/1024)
    float wsr, wsi, w16r, w16i;
    sincosf(C * (float)mu, &wsi, &wsr);
    sincosf(C * (float)((mu * 16) & 1023), &w16i, &w16r);

    float dr[4] = {0,0,0,0}, di[4] = {0,0,0,0};
    float nr[4] = {0,0,0,0}, ni[4] = {0,0,0,0};
    float wrefr = 1.f, wrefi = 0.f;

    for (int mo = 0; mo < 32; ++mo) {
        float wr = wrefr, wi = wrefi;
        #pragma unroll
        for (int mi = 0; mi < 16; ++mi) {
            const int m = mo * 16 + mi;
            const float4 k01 = *(const float4*)&gk[m][0];
            const float4 k23 = *(const float4*)&gk[m][2];
            const float4 p01 = *(const float4*)&gp[m][0];
            const float4 p23 = *(const float4*)&gp[m][2];

            dr[0] = fmaf(k01.x, wr, dr[0]); dr[0] = fmaf(-k01.y, wi, dr[0]);
            di[0] = fmaf(k01.x, wi, di[0]); di[0] = fmaf( k01.y, wr, di[0]);
            dr[1] = fmaf(k01.z, wr, dr[1]); dr[1] = fmaf(-k01.w, wi, dr[1]);
            di[1] = fmaf(k01.z, wi, di[1]); di[1] = fmaf( k01.w, wr, di[1]);
            dr[2] = fmaf(k23.x, wr, dr[2]); dr[2] = fmaf(-k23.y, wi, dr[2]);
            di[2] = fmaf(k23.x, wi, di[2]); di[2] = fmaf( k23.y, wr, di[2]);
            dr[3] = fmaf(k23.z, wr, dr[3]); dr[3] = fmaf(-k23.w, wi, dr[3]);
            di[3] = fmaf(k23.z, wi, di[3]); di[3] = fmaf( k23.w, wr, di[3]);

            nr[0] = fmaf(p01.x, wr, nr[0]); nr[0] = fmaf(-p01.y, wi, nr[0]);
            ni[0] = fmaf(p01.x, wi, ni[0]); ni[0] = fmaf( p01.y, wr, ni[0]);
            nr[1] = fmaf(p01.z, wr, nr[1]); nr[1] = fmaf(-p01.w, wi, nr[1]);
            ni[1] = fmaf(p01.z, wi, ni[1]); ni[1] = fmaf( p01.w, wr, ni[1]);
            nr[2] = fmaf(p23.x, wr, nr[2]); nr[2] = fmaf(-p23.y, wi, nr[2]);
            ni[2] = fmaf(p23.x, wi, ni[2]); ni[2] = fmaf( p23.y, wr, ni[2]);
            nr[3] = fmaf(p23.z, wr, nr[3]); nr[3] = fmaf(-p23.w, wi, nr[3]);
            ni[3] = fmaf(p23.z, wi, ni[3]); ni[3] = fmaf( p23.w, wr, ni[3]);

            const float nwr = wr * wsr - wi * wsi;
            wi = fmaf(wr, wsi, wi * wsr);
            wr = nwr;
        }
        const float nwr = wrefr * w16r - wrefi * w16i;
        wrefi = fmaf(wrefr, w16i, wrefi * w16r);
        wrefr = nwr;
    }

    if (out_cplx) {
        float2 res[4];
        #pragma unroll
        for (int z = 0; z < 4; ++z) {
            const float dmag = dr[z] * dr[z] + di[z] * di[z];
            res[z].x = (nr[z] * dr[z] + ni[z] * di[z]) / dmag;
            res[z].y = (ni[z] * dr[z] - nr[z] * di[z]) / dmag;
        }
        float2* out2 = (float2*)out;
        const size_t o0 = ((size_t)be * NPOS + mu) * 64 + zg * 4;
        *(float4*)&out2[o0]     = make_float4(res[0].x, res[0].y, res[1].x, res[1].y);
        *(float4*)&out2[o0 + 2] = make_float4(res[2].x, res[2].y, res[3].x, res[3].y);
    } else {
        const size_t o0 = ((size_t)be * NPOS + mu) * 64 + zg * 4;
        #pragma unroll
        for (int z = 0; z < 4; ++z) {
            const float dmag = dr[z] * dr[z] + di[z] * di[z];
            out[o0 + z] = (nr[z] * dr[z] + ni[z] * di[z]) / dmag;
        }
    }
}

// Fallback mdft (proven, fp64) for the ws-aliasing path: block = (be,z),
// self-contained over all mu, safe when Gp aliases d_out.
__global__ __launch_bounds__(256)
void mdft_fallback_kernel(const float2* __restrict__ Gk,
                          const float2* __restrict__ Gp,
                          float* __restrict__ out,
                          int out_cplx)
{
    const int blk = blockIdx.x;
    const int be = blk >> 6, z = blk & 63;
    const int t = threadIdx.x;
    __shared__ float2 gk[512];
    __shared__ float2 gp[512];
    __shared__ float2 w[1024];

    for (int m = t; m < 512; m += 256) {
        const size_t idx = ((size_t)be * NPOS + m) * 64 + z;
        gk[m] = Gk[idx];
        gp[m] = Gp[idx];
    }
    for (int j = t; j < 1024; j += 256) {
        double s, c;
        sincos(-6.2831853071795864769 * (double)j / 1024.0, &s, &c);
        w[j] = make_float2((float)c, (float)s);
    }
    __syncthreads();

    #pragma unroll
    for (int half = 0; half < 2; ++half) {
        const int mu = t + half * 256;
        double dr = 0.0, di = 0.0, nr = 0.0, ni = 0.0;
        int idx = 0;
        for (int m = 0; m < 512; ++m) {
            const float2 tw = w[idx];
            idx = (idx + mu) & 1023;
            const float2 a = gk[m];
            dr += (double)(a.x * tw.x - a.y * tw.y);
            di += (double)(a.x * tw.y + a.y * tw.x);
            const float2 p = gp[m];
            nr += (double)(p.x * tw.x - p.y * tw.y);
            ni += (double)(p.x * tw.y + p.y * tw.x);
        }
        const double dmag = dr * dr + di * di;
        const double orr = (nr * dr + ni * di) / dmag;
        const double oii = (ni * dr - nr * di) / dmag;
        const size_t o = ((size_t)be * NPOS + mu) * 64 + z;
        if (out_cplx) {
            out[2 * o]     = (float)orr;
            out[2 * o + 1] = (float)oii;
        } else {
            out[o] = (float)orr;
        }
    }
}

extern "C" void kernel_launch(void* const* d_in, const int* in_sizes, int n_in,
                              void* d_out, int out_size, void* d_ws, size_t ws_size,
                              hipStream_t stream)
{
    // setup_inputs order: x, Wq, Wk, Wv, Er — only x, Wk, Wv are needed
    const float* x  = (const float*)d_in[0];
    const float* Wk = (const float*)d_in[2];
    const float* Wv = (const float*)d_in[3];
    float* out = (float*)d_out;

    char* ws = (char*)d_ws;
    float*  K   = (float*)(ws);                           // 2 MB
    float*  V   = (float*)(ws + (size_t)2097152);         // 2 MB
    float2* Gk  = (float2*)(ws + (size_t)4194304);        // 4 MB
    double* ssq = (double*)(ws + (size_t)8388608);        // 8 B
    const int out_cplx = (out_size >= 2 * 2 * 8 * 512 * 64) ? 1 : 0;

    const bool ws_big = (ws_size >= (size_t)8388672 + (size_t)4194304);
    float2* Gp = ws_big ? (float2*)(ws + (size_t)8388672)  // 4 MB
                        : (float2*)d_out;                  // alias-safe fallback

    hipMemsetAsync(ssq, 0, sizeof(double), stream);
    hipLaunchKernelGGL(gemm_kv_kernel, dim3(256), dim3(256), 0, stream,
                       x, Wk, Wv, K, V, ssq);
    hipLaunchKernelGGL(stage1_kernel, dim3(512), dim3(256), 0, stream,
                       K, V, ssq, Gk, Gp);
    if (ws_big) {
        hipLaunchKernelGGL(mdft_v2_kernel, dim3(512), dim3(256), 0, stream,
                           Gk, Gp, out, out_cplx);
    } else {
        hipLaunchKernelGGL(mdft_fallback_kernel, dim3(1024), dim3(256), 0, stream,
                           Gk, Gp, out, out_cplx);
    }
}

// Round 3
// 129.029 us; speedup vs baseline: 2.5455x; 1.4886x over previous
//
#include <hip/hip_runtime.h>
#include <math.h>

// B=2, N=512, DIM=512, HEADS=8, DIM_HEAD=64
// out[be,mu,z] = FFT1024(S_k*v)[mu] / FFT1024(k_)[mu],  mu in [0,512)
// after a 2x8 (b,h)-DFT; inputs zero-padded 512 -> 1024 on the m axis.

#define DIMX 512
#define NPOS 512
#define PADIDX(m) ((m) + ((m) >> 4))

// ---------------- GEMM: 16x128 tiles, 512 blocks (2/CU) ----------------
__global__ __launch_bounds__(256)
void gemm_kv_kernel(const float* __restrict__ x,
                    const float* __restrict__ Wk,
                    const float* __restrict__ Wv,
                    float* __restrict__ K,
                    float* __restrict__ V,
                    double* __restrict__ sumsq)
{
    const int sel  = blockIdx.x >> 8;        // 0 -> K, 1 -> V (256 tiles each)
    const int tid  = blockIdx.x & 255;
    const int row0 = (tid >> 2) * 16;        // 64 row-tiles
    const int col0 = (tid & 3) * 128;        // 4 col-tiles
    const int t    = threadIdx.x;
    const int c    = t & 63;                 // cols col0+c, col0+c+64
    const int rg   = t >> 6;                 // 4 row-groups of 4 rows
    const float* __restrict__ W   = sel ? Wv : Wk;
    float* __restrict__       Out = sel ? V  : K;

    __shared__ float xs[16][DIMX];           // 32 KB
    __shared__ float red[4];

    for (int e = t; e < 16 * DIMX; e += 256)
        xs[e >> 9][e & 511] = x[(size_t)(row0 + (e >> 9)) * DIMX + (e & 511)];
    __syncthreads();

    float acc0[4] = {0,0,0,0}, acc1[4] = {0,0,0,0};
    for (int k = 0; k < DIMX; k += 4) {
        float w0[4], w1[4];
        #pragma unroll
        for (int j = 0; j < 4; ++j) {
            w0[j] = W[(size_t)(k + j) * DIMX + col0 + c];
            w1[j] = W[(size_t)(k + j) * DIMX + col0 + c + 64];
        }
        #pragma unroll
        for (int i = 0; i < 4; ++i) {
            const float4 xv = *(const float4*)&xs[rg * 4 + i][k];
            acc0[i] = fmaf(xv.x, w0[0], acc0[i]);
            acc0[i] = fmaf(xv.y, w0[1], acc0[i]);
            acc0[i] = fmaf(xv.z, w0[2], acc0[i]);
            acc0[i] = fmaf(xv.w, w0[3], acc0[i]);
            acc1[i] = fmaf(xv.x, w1[0], acc1[i]);
            acc1[i] = fmaf(xv.y, w1[1], acc1[i]);
            acc1[i] = fmaf(xv.z, w1[2], acc1[i]);
            acc1[i] = fmaf(xv.w, w1[3], acc1[i]);
        }
    }

    float ss = 0.f;
    #pragma unroll
    for (int i = 0; i < 4; ++i) {
        const int row = row0 + rg * 4 + i;
        Out[(size_t)row * DIMX + col0 + c]      = acc0[i];
        Out[(size_t)row * DIMX + col0 + c + 64] = acc1[i];
        ss += acc0[i] * acc0[i] + acc1[i] * acc1[i];
    }
    if (sel == 0) {   // Frobenius sumsq of K
        #pragma unroll
        for (int off = 32; off > 0; off >>= 1)
            ss += __shfl_down(ss, off, 64);
        if ((t & 63) == 0) red[t >> 6] = ss;
        __syncthreads();
        if (t == 0) {
            double tot = (double)red[0] + (double)red[1] + (double)red[2] + (double)red[3];
            atomicAdd(sumsq, tot);
        }
    }
}

// 8-point DFT twiddles: exp(-2*pi*i*k/8)
__device__ __constant__ float C8[8] = {
    1.f, 0.70710678118654752440f, 0.f, -0.70710678118654752440f,
   -1.f, -0.70710678118654752440f, 0.f, 0.70710678118654752440f };
__device__ __constant__ float S8[8] = {
    0.f, -0.70710678118654752440f, -1.f, -0.70710678118654752440f,
    0.f,  0.70710678118654752440f,  1.f,  0.70710678118654752440f };

// elu(K/norm), S_k, P = S_k*V, 2x8 (b,h)-DFT.
// layout=1: Gk/Gp as [be][z][m] (m fastest, for FFT); layout=0: [be][m][z].
__global__ __launch_bounds__(256)
void stage1_kernel(const float* __restrict__ K,
                   const float* __restrict__ V,
                   const double* __restrict__ sumsq,
                   float2* __restrict__ Gk,
                   float2* __restrict__ Gp,
                   int layout)
{
    const int m = blockIdx.x;     // 0..511
    const int t = threadIdx.x;
    __shared__ float kk[2][8][64];
    __shared__ float pp[2][8][64];
    __shared__ float sk[2][8];

    const float scale = (float)(1.0 / sqrt(*sumsq));

    for (int e = t; e < 1024; e += 256) {
        const int b = e >> 9, rem = e & 511, h = rem >> 6, z = rem & 63;
        const size_t src = (size_t)(b * 512 + m) * DIMX + h * 64 + z;
        const float kv = K[src] * scale;
        kk[b][h][z] = kv > 0.f ? kv : expm1f(kv);
        pp[b][h][z] = V[src];
    }
    __syncthreads();
    if (t < 16) {
        const int b = t >> 3, h = t & 7;
        float s = 0.f;
        #pragma unroll
        for (int z = 0; z < 64; ++z) s += kk[b][h][z];
        sk[b][h] = s;
    }
    __syncthreads();
    for (int e = t; e < 1024; e += 256) {
        const int b = e >> 9, rem = e & 511, h = rem >> 6, z = rem & 63;
        pp[b][h][z] *= sk[b][h];
    }
    __syncthreads();
    for (int e = t; e < 1024; e += 256) {
        const int be = e >> 6;
        const int z  = e & 63;
        const int beta = be >> 3, eta = be & 7;
        float gkr = 0.f, gki = 0.f, gpr = 0.f, gpi = 0.f;
        #pragma unroll
        for (int b = 0; b < 2; ++b) {
            const float sgn = (beta & b) ? -1.f : 1.f;
            #pragma unroll
            for (int h = 0; h < 8; ++h) {
                const int ph = (eta * h) & 7;
                const float cr = C8[ph], ci = S8[ph];
                const float a = kk[b][h][z] * sgn;
                gkr = fmaf(a, cr, gkr); gki = fmaf(a, ci, gki);
                const float p = pp[b][h][z] * sgn;
                gpr = fmaf(p, cr, gpr); gpi = fmaf(p, ci, gpi);
            }
        }
        const size_t o = layout ? ((size_t)(be * 64 + z)) * NPOS + m
                                : ((size_t)be * NPOS + m) * 64 + z;
        Gk[o] = make_float2(gkr, gki);
        Gp[o] = make_float2(gpr, gpi);
    }
}

// ---------------- Zero-padded 1024-pt radix-2 DIF FFT + divide ----------------
// Grid 512: blk = be*32 + zg; block handles z = {2*zg, 2*zg+1}, 4 transforms
// (k,p x 2 z) of length 1024 in LDS. Output bit-reversed order handled at the
// final divide: work[2i] = X[bitrev9(i)], i in [0,512).
__global__ __launch_bounds__(256)
void fft_div_kernel(const float2* __restrict__ Gk,   // [be][z][m]
                    const float2* __restrict__ Gp,
                    float* __restrict__ out, int out_cplx)
{
    const int be = blockIdx.x >> 5;
    const int zg = blockIdx.x & 31;
    const int t  = threadIdx.x;

    __shared__ float2 g[4][1088];   // arr = a*2+zi, padded 1024 -> 1088
    __shared__ float2 w[544];       // padded 512 twiddles

    for (int j = t; j < 512; j += 256) {
        double s, cc;
        sincos(-6.2831853071795864769 * (double)j / 1024.0, &s, &cc);
        w[PADIDX(j)] = make_float2((float)cc, (float)s);
    }
    __syncthreads();

    // load + fused stage 0 (upper half of input is zero):
    // g[m] = val ; g[m+512] = val * W_1024^m
    for (int e = t; e < 2048; e += 256) {
        const int arr = e >> 9;          // a*2+zi
        const int m   = e & 511;
        const int a = arr >> 1, zi = arr & 1;
        const float2 val = (a ? Gp : Gk)[((size_t)be * 64 + zg * 2 + zi) * NPOS + m];
        const float2 tw = w[PADIDX(m)];
        g[arr][PADIDX(m)]       = val;
        g[arr][PADIDX(m + 512)] = make_float2(val.x * tw.x - val.y * tw.y,
                                              val.x * tw.y + val.y * tw.x);
    }
    __syncthreads();

    #pragma unroll
    for (int s = 1; s <= 9; ++s) {
        const int S = 512 >> s;          // butterfly span
        const int l = 9 - s;             // log2(S)
        #pragma unroll
        for (int q = 0; q < 8; ++q) {
            const int B    = t + 256 * q;     // 2048 butterflies/stage/block
            const int arr  = B >> 9;
            const int beta = B & 511;
            const int j    = beta & (S - 1);
            const int seg  = beta >> l;
            const int u    = (seg << (l + 1)) + j;
            const int v    = u + S;
            const float2 tw = w[PADIDX(j << s)];
            const float2 A  = g[arr][PADIDX(u)];
            const float2 Bb = g[arr][PADIDX(v)];
            g[arr][PADIDX(u)] = make_float2(A.x + Bb.x, A.y + Bb.y);
            const float sr = A.x - Bb.x, si = A.y - Bb.y;
            g[arr][PADIDX(v)] = make_float2(sr * tw.x - si * tw.y,
                                            sr * tw.y + si * tw.x);
        }
        __syncthreads();
    }

    // even positions 2i hold mu = bitrev9(i) (mu<512). Divide and store.
    for (int e = t; e < 1024; e += 256) {
        const int zi = e & 1;
        const int i  = e >> 1;
        const int pi = PADIDX(2 * i);
        const int mu = (int)(__brev((unsigned)i) >> 23);   // bitrev9
        const float2 D  = g[zi][pi];
        const float2 Nm = g[2 + zi][pi];
        const float inv = 1.f / (D.x * D.x + D.y * D.y);
        const float rr = (Nm.x * D.x + Nm.y * D.y) * inv;
        const float ri = (Nm.y * D.x - Nm.x * D.y) * inv;
        const size_t o = ((size_t)be * NPOS + mu) * 64 + zg * 2 + zi;
        if (out_cplx) ((float2*)out)[o] = make_float2(rr, ri);
        else          out[o] = rr;
    }
}

// Fallback mdft (fp64, [be][m][z] layout) for the ws-aliasing path.
__global__ __launch_bounds__(256)
void mdft_fallback_kernel(const float2* __restrict__ Gk,
                          const float2* __restrict__ Gp,
                          float* __restrict__ out,
                          int out_cplx)
{
    const int blk = blockIdx.x;
    const int be = blk >> 6, z = blk & 63;
    const int t = threadIdx.x;
    __shared__ float2 gk[512];
    __shared__ float2 gp[512];
    __shared__ float2 w[1024];

    for (int m = t; m < 512; m += 256) {
        const size_t idx = ((size_t)be * NPOS + m) * 64 + z;
        gk[m] = Gk[idx];
        gp[m] = Gp[idx];
    }
    for (int j = t; j < 1024; j += 256) {
        double s, c;
        sincos(-6.2831853071795864769 * (double)j / 1024.0, &s, &c);
        w[j] = make_float2((float)c, (float)s);
    }
    __syncthreads();

    #pragma unroll
    for (int half = 0; half < 2; ++half) {
        const int mu = t + half * 256;
        double dr = 0.0, di = 0.0, nr = 0.0, ni = 0.0;
        int idx = 0;
        for (int m = 0; m < 512; ++m) {
            const float2 tw = w[idx];
            idx = (idx + mu) & 1023;
            const float2 a = gk[m];
            dr += (double)(a.x * tw.x - a.y * tw.y);
            di += (double)(a.x * tw.y + a.y * tw.x);
            const float2 p = gp[m];
            nr += (double)(p.x * tw.x - p.y * tw.y);
            ni += (double)(p.x * tw.y + p.y * tw.x);
        }
        const double dmag = dr * dr + di * di;
        const double orr = (nr * dr + ni * di) / dmag;
        const double oii = (ni * dr - nr * di) / dmag;
        const size_t o = ((size_t)be * NPOS + mu) * 64 + z;
        if (out_cplx) {
            out[2 * o]     = (float)orr;
            out[2 * o + 1] = (float)oii;
        } else {
            out[o] = (float)orr;
        }
    }
}

extern "C" void kernel_launch(void* const* d_in, const int* in_sizes, int n_in,
                              void* d_out, int out_size, void* d_ws, size_t ws_size,
                              hipStream_t stream)
{
    // inputs: x, Wq, Wk, Wv, Er — only x, Wk, Wv needed
    const float* x  = (const float*)d_in[0];
    const float* Wk = (const float*)d_in[2];
    const float* Wv = (const float*)d_in[3];
    float* out = (float*)d_out;

    char* ws = (char*)d_ws;
    float*  K   = (float*)(ws);                           // 2 MB
    float*  V   = (float*)(ws + (size_t)2097152);         // 2 MB
    float2* Gk  = (float2*)(ws + (size_t)4194304);        // 4 MB
    double* ssq = (double*)(ws + (size_t)8388608);        // 8 B
    const int out_cplx = (out_size >= 2 * 2 * 8 * 512 * 64) ? 1 : 0;

    const bool ws_big = (ws_size >= (size_t)8388672 + (size_t)4194304);
    float2* Gp = ws_big ? (float2*)(ws + (size_t)8388672)  // 4 MB
                        : (float2*)d_out;                  // alias-safe fallback

    hipMemsetAsync(ssq, 0, sizeof(double), stream);
    hipLaunchKernelGGL(gemm_kv_kernel, dim3(512), dim3(256), 0, stream,
                       x, Wk, Wv, K, V, ssq);
    hipLaunchKernelGGL(stage1_kernel, dim3(512), dim3(256), 0, stream,
                       K, V, ssq, Gk, Gp, ws_big ? 1 : 0);
    if (ws_big) {
        hipLaunchKernelGGL(fft_div_kernel, dim3(512), dim3(256), 0, stream,
                           Gk, Gp, out, out_cplx);
    } else {
        hipLaunchKernelGGL(mdft_fallback_kernel, dim3(1024), dim3(256), 0, stream,
                           Gk, Gp, out, out_cplx);
    }
}

// Round 4
// 127.561 us; speedup vs baseline: 2.5748x; 1.0115x over previous
//
#include <hip/hip_runtime.h>
#include <math.h>

// B=2, N=512, DIM=512, HEADS=8, DIM_HEAD=64
// out[be,mu,z] = FFT1024(S_k*v)[mu] / FFT1024(k_)[mu],  mu in [0,512)
// after a 2x8 (b,h)-DFT; inputs zero-padded 512 -> 1024 on the m axis.

#define DIMX 512
#define NPOS 512
#define PADIDX(m) ((m) + ((m) >> 4))

// ---------------- GEMM v3: 32x128 tiles, grid 256 (1/CU), LDS dbuf ----------
// Thread (tc 0..31, tr 0..7) computes 4 rows x 4 cols. x reads are wave
// broadcasts (addr depends on tr only); W reads are float4/lane. Per k:
// 16 FMA-inst vs 5 ds_reads -> VALU-issue-bound, not LDS/latency-bound.
__global__ __launch_bounds__(256)
void gemm_kv_kernel(const float* __restrict__ x,
                    const float* __restrict__ Wk,
                    const float* __restrict__ Wv,
                    float* __restrict__ K,
                    float* __restrict__ V,
                    float* __restrict__ partials)
{
    const int blk  = blockIdx.x;          // 0..255
    const int sel  = blk >> 7;            // 0 -> K, 1 -> V
    const int tid  = blk & 127;
    const int row0 = (tid >> 2) * 32;     // 32 row-tiles
    const int col0 = (tid & 3) * 128;     // 4 col-tiles
    const int t    = threadIdx.x;
    const int tc   = t & 31;
    const int tr   = t >> 5;              // 0..7
    const float* __restrict__ W   = sel ? Wv : Wk;
    float* __restrict__       Out = sel ? V  : K;

    __shared__ float xs[2][32][33];       // [buf][row][k], pad 33
    __shared__ float ws[2][32][128];      // [buf][k][col]
    __shared__ float red[4];

    float acc[4][4] = {{0,0,0,0},{0,0,0,0},{0,0,0,0},{0,0,0,0}};
    float  xr[4];
    float4 wv4[4];

    // ---- global loads for k-chunk kb (32 k) into registers ----
    #define LD_GLOBAL(kb)                                                      \
        {   _Pragma("unroll")                                                  \
            for (int j = 0; j < 4; ++j) {                                      \
                const int idx = t + j * 256;                                   \
                xr[j] = x[(size_t)(row0 + (idx >> 5)) * DIMX + (kb) + (idx & 31)]; \
            }                                                                  \
            _Pragma("unroll")                                                  \
            for (int j = 0; j < 4; ++j) {                                      \
                const int f4 = t + j * 256;                                    \
                const int kk = f4 >> 5, cp = (f4 & 31) * 4;                    \
                wv4[j] = *(const float4*)&W[(size_t)((kb) + kk) * DIMX + col0 + cp]; \
            } }

    #define ST_LDS(buf)                                                        \
        {   _Pragma("unroll")                                                  \
            for (int j = 0; j < 4; ++j) {                                      \
                const int idx = t + j * 256;                                   \
                xs[buf][idx >> 5][idx & 31] = xr[j];                           \
            }                                                                  \
            _Pragma("unroll")                                                  \
            for (int j = 0; j < 4; ++j) {                                      \
                const int f4 = t + j * 256;                                    \
                const int kk = f4 >> 5, cp = (f4 & 31) * 4;                    \
                *(float4*)&ws[buf][kk][cp] = wv4[j];                           \
            } }

    LD_GLOBAL(0)
    ST_LDS(0)
    __syncthreads();

    for (int kb = 0; kb < 16; ++kb) {
        const int cur = kb & 1;
        if (kb < 15) LD_GLOBAL((kb + 1) * 32)
        #pragma unroll
        for (int kk = 0; kk < 32; ++kk) {
            const float4 w4 = *(const float4*)&ws[cur][kk][tc * 4];
            float xv[4];
            #pragma unroll
            for (int i = 0; i < 4; ++i) xv[i] = xs[cur][tr * 4 + i][kk];
            #pragma unroll
            for (int i = 0; i < 4; ++i) {
                acc[i][0] = fmaf(xv[i], w4.x, acc[i][0]);
                acc[i][1] = fmaf(xv[i], w4.y, acc[i][1]);
                acc[i][2] = fmaf(xv[i], w4.z, acc[i][2]);
                acc[i][3] = fmaf(xv[i], w4.w, acc[i][3]);
            }
        }
        if (kb < 15) {
            __syncthreads();
            ST_LDS(1 - cur)
            __syncthreads();
        }
    }

    float ss = 0.f;
    #pragma unroll
    for (int i = 0; i < 4; ++i) {
        const int row = row0 + tr * 4 + i;
        const float4 o = make_float4(acc[i][0], acc[i][1], acc[i][2], acc[i][3]);
        *(float4*)&Out[(size_t)row * DIMX + col0 + tc * 4] = o;
        ss += o.x * o.x + o.y * o.y + o.z * o.z + o.w * o.w;
    }
    if (sel == 0) {   // Frobenius sumsq of K -> per-block partial
        #pragma unroll
        for (int off = 32; off > 0; off >>= 1)
            ss += __shfl_down(ss, off, 64);
        if ((t & 63) == 0) red[t >> 6] = ss;
        __syncthreads();
        if (t == 0) partials[blk] = red[0] + red[1] + red[2] + red[3];
    } else {
        if (t == 0) partials[blk] = 0.f;
    }
    #undef LD_GLOBAL
    #undef ST_LDS
}

// 8-point DFT twiddles: exp(-2*pi*i*k/8)
__device__ __constant__ float C8[8] = {
    1.f, 0.70710678118654752440f, 0.f, -0.70710678118654752440f,
   -1.f, -0.70710678118654752440f, 0.f, 0.70710678118654752440f };
__device__ __constant__ float S8[8] = {
    0.f, -0.70710678118654752440f, -1.f, -0.70710678118654752440f,
    0.f,  0.70710678118654752440f,  1.f,  0.70710678118654752440f };

// elu(K/norm), S_k, P = S_k*V, 2x8 (b,h)-DFT.
// layout=1: Gk/Gp as [be][z][m] (m fastest, for FFT); layout=0: [be][m][z].
__global__ __launch_bounds__(256)
void stage1_kernel(const float* __restrict__ K,
                   const float* __restrict__ V,
                   const float* __restrict__ partials,
                   float2* __restrict__ Gk,
                   float2* __restrict__ Gp,
                   int layout)
{
    const int m = blockIdx.x;     // 0..511
    const int t = threadIdx.x;
    __shared__ float kk[2][8][64];
    __shared__ float pp[2][8][64];
    __shared__ float sk[2][8];
    __shared__ float sred[4];

    // reduce the 256 gemm partials -> global Frobenius scale
    float p = partials[t];
    #pragma unroll
    for (int off = 32; off > 0; off >>= 1)
        p += __shfl_down(p, off, 64);
    if ((t & 63) == 0) sred[t >> 6] = p;
    __syncthreads();
    const float scale = (float)(1.0 / sqrt((double)sred[0] + (double)sred[1] +
                                           (double)sred[2] + (double)sred[3]));

    for (int e = t; e < 1024; e += 256) {
        const int b = e >> 9, rem = e & 511, h = rem >> 6, z = rem & 63;
        const size_t src = (size_t)(b * 512 + m) * DIMX + h * 64 + z;
        const float kv = K[src] * scale;
        kk[b][h][z] = kv > 0.f ? kv : expm1f(kv);
        pp[b][h][z] = V[src];
    }
    __syncthreads();
    if (t < 16) {
        const int b = t >> 3, h = t & 7;
        float s = 0.f;
        #pragma unroll
        for (int z = 0; z < 64; ++z) s += kk[b][h][z];
        sk[b][h] = s;
    }
    __syncthreads();
    for (int e = t; e < 1024; e += 256) {
        const int b = e >> 9, rem = e & 511, h = rem >> 6, z = rem & 63;
        pp[b][h][z] *= sk[b][h];
    }
    __syncthreads();
    for (int e = t; e < 1024; e += 256) {
        const int be = e >> 6;
        const int z  = e & 63;
        const int beta = be >> 3, eta = be & 7;
        float gkr = 0.f, gki = 0.f, gpr = 0.f, gpi = 0.f;
        #pragma unroll
        for (int b = 0; b < 2; ++b) {
            const float sgn = (beta & b) ? -1.f : 1.f;
            #pragma unroll
            for (int h = 0; h < 8; ++h) {
                const int ph = (eta * h) & 7;
                const float cr = C8[ph], ci = S8[ph];
                const float a = kk[b][h][z] * sgn;
                gkr = fmaf(a, cr, gkr); gki = fmaf(a, ci, gki);
                const float p2 = pp[b][h][z] * sgn;
                gpr = fmaf(p2, cr, gpr); gpi = fmaf(p2, ci, gpi);
            }
        }
        const size_t o = layout ? ((size_t)(be * 64 + z)) * NPOS + m
                                : ((size_t)be * NPOS + m) * 64 + z;
        Gk[o] = make_float2(gkr, gki);
        Gp[o] = make_float2(gpr, gpi);
    }
}

// ---------------- Zero-padded 1024-pt radix-2 DIF FFT + divide ----------------
__global__ __launch_bounds__(256)
void fft_div_kernel(const float2* __restrict__ Gk,   // [be][z][m]
                    const float2* __restrict__ Gp,
                    float* __restrict__ out, int out_cplx)
{
    const int be = blockIdx.x >> 5;
    const int zg = blockIdx.x & 31;
    const int t  = threadIdx.x;

    __shared__ float2 g[4][1088];   // arr = a*2+zi, padded 1024 -> 1088
    __shared__ float2 w[544];       // padded 512 twiddles

    for (int j = t; j < 512; j += 256) {
        double s, cc;
        sincos(-6.2831853071795864769 * (double)j / 1024.0, &s, &cc);
        w[PADIDX(j)] = make_float2((float)cc, (float)s);
    }
    __syncthreads();

    for (int e = t; e < 2048; e += 256) {
        const int arr = e >> 9;          // a*2+zi
        const int m   = e & 511;
        const int a = arr >> 1, zi = arr & 1;
        const float2 val = (a ? Gp : Gk)[((size_t)be * 64 + zg * 2 + zi) * NPOS + m];
        const float2 tw = w[PADIDX(m)];
        g[arr][PADIDX(m)]       = val;
        g[arr][PADIDX(m + 512)] = make_float2(val.x * tw.x - val.y * tw.y,
                                              val.x * tw.y + val.y * tw.x);
    }
    __syncthreads();

    #pragma unroll
    for (int s = 1; s <= 9; ++s) {
        const int S = 512 >> s;
        const int l = 9 - s;
        #pragma unroll
        for (int q = 0; q < 8; ++q) {
            const int B    = t + 256 * q;
            const int arr  = B >> 9;
            const int beta = B & 511;
            const int j    = beta & (S - 1);
            const int seg  = beta >> l;
            const int u    = (seg << (l + 1)) + j;
            const int v    = u + S;
            const float2 tw = w[PADIDX(j << s)];
            const float2 A  = g[arr][PADIDX(u)];
            const float2 Bb = g[arr][PADIDX(v)];
            g[arr][PADIDX(u)] = make_float2(A.x + Bb.x, A.y + Bb.y);
            const float sr = A.x - Bb.x, si = A.y - Bb.y;
            g[arr][PADIDX(v)] = make_float2(sr * tw.x - si * tw.y,
                                            sr * tw.y + si * tw.x);
        }
        __syncthreads();
    }

    for (int e = t; e < 1024; e += 256) {
        const int zi = e & 1;
        const int i  = e >> 1;
        const int pi = PADIDX(2 * i);
        const int mu = (int)(__brev((unsigned)i) >> 23);   // bitrev9
        const float2 D  = g[zi][pi];
        const float2 Nm = g[2 + zi][pi];
        const float inv = 1.f / (D.x * D.x + D.y * D.y);
        const float rr = (Nm.x * D.x + Nm.y * D.y) * inv;
        const float ri = (Nm.y * D.x - Nm.x * D.y) * inv;
        const size_t o = ((size_t)be * NPOS + mu) * 64 + zg * 2 + zi;
        if (out_cplx) ((float2*)out)[o] = make_float2(rr, ri);
        else          out[o] = rr;
    }
}

// Fallback mdft (fp64, [be][m][z] layout) for the ws-aliasing path.
__global__ __launch_bounds__(256)
void mdft_fallback_kernel(const float2* __restrict__ Gk,
                          const float2* __restrict__ Gp,
                          float* __restrict__ out,
                          int out_cplx)
{
    const int blk = blockIdx.x;
    const int be = blk >> 6, z = blk & 63;
    const int t = threadIdx.x;
    __shared__ float2 gk[512];
    __shared__ float2 gp[512];
    __shared__ float2 w[1024];

    for (int m = t; m < 512; m += 256) {
        const size_t idx = ((size_t)be * NPOS + m) * 64 + z;
        gk[m] = Gk[idx];
        gp[m] = Gp[idx];
    }
    for (int j = t; j < 1024; j += 256) {
        double s, c;
        sincos(-6.2831853071795864769 * (double)j / 1024.0, &s, &c);
        w[j] = make_float2((float)c, (float)s);
    }
    __syncthreads();

    #pragma unroll
    for (int half = 0; half < 2; ++half) {
        const int mu = t + half * 256;
        double dr = 0.0, di = 0.0, nr = 0.0, ni = 0.0;
        int idx = 0;
        for (int m = 0; m < 512; ++m) {
            const float2 tw = w[idx];
            idx = (idx + mu) & 1023;
            const float2 a = gk[m];
            dr += (double)(a.x * tw.x - a.y * tw.y);
            di += (double)(a.x * tw.y + a.y * tw.x);
            const float2 p = gp[m];
            nr += (double)(p.x * tw.x - p.y * tw.y);
            ni += (double)(p.x * tw.y + p.y * tw.x);
        }
        const double dmag = dr * dr + di * di;
        const double orr = (nr * dr + ni * di) / dmag;
        const double oii = (ni * dr - nr * di) / dmag;
        const size_t o = ((size_t)be * NPOS + mu) * 64 + z;
        if (out_cplx) {
            out[2 * o]     = (float)orr;
            out[2 * o + 1] = (float)oii;
        } else {
            out[o] = (float)orr;
        }
    }
}

extern "C" void kernel_launch(void* const* d_in, const int* in_sizes, int n_in,
                              void* d_out, int out_size, void* d_ws, size_t ws_size,
                              hipStream_t stream)
{
    // inputs: x, Wq, Wk, Wv, Er — only x, Wk, Wv needed
    const float* x  = (const float*)d_in[0];
    const float* Wk = (const float*)d_in[2];
    const float* Wv = (const float*)d_in[3];
    float* out = (float*)d_out;

    char* ws = (char*)d_ws;
    float*  K    = (float*)(ws);                           // 2 MB
    float*  V    = (float*)(ws + (size_t)2097152);         // 2 MB
    float2* Gk   = (float2*)(ws + (size_t)4194304);        // 4 MB
    float*  part = (float*)(ws + (size_t)8388608);         // 1 KB (256 floats)
    const int out_cplx = (out_size >= 2 * 2 * 8 * 512 * 64) ? 1 : 0;

    const bool ws_big = (ws_size >= (size_t)8390656 + (size_t)4194304);
    float2* Gp = ws_big ? (float2*)(ws + (size_t)8390656)  // 4 MB
                        : (float2*)d_out;                  // alias-safe fallback

    hipLaunchKernelGGL(gemm_kv_kernel, dim3(256), dim3(256), 0, stream,
                       x, Wk, Wv, K, V, part);
    hipLaunchKernelGGL(stage1_kernel, dim3(512), dim3(256), 0, stream,
                       K, V, part, Gk, Gp, ws_big ? 1 : 0);
    if (ws_big) {
        hipLaunchKernelGGL(fft_div_kernel, dim3(512), dim3(256), 0, stream,
                           Gk, Gp, out, out_cplx);
    } else {
        hipLaunchKernelGGL(mdft_fallback_kernel, dim3(1024), dim3(256), 0, stream,
                           Gk, Gp, out, out_cplx);
    }
}

// Round 5
// 116.469 us; speedup vs baseline: 2.8200x; 1.0952x over previous
//
#include <hip/hip_runtime.h>
#include <math.h>

// B=2, N=512, DIM=512, HEADS=8, DIM_HEAD=64
// out[be,mu,z] = FFT1024(S_k*v)[mu] / FFT1024(k_)[mu],  mu in [0,512)
// after a 2x8 (b,h)-DFT; inputs zero-padded 512 -> 1024 on the m axis.
// Gk/Gp layout: [be][m][z] (z fastest) -> stage1 writes coalesced;
// fft_div reads z-pairs as float4 at stride 512 B (L2-resident).

#define DIMX 512
#define NPOS 512
#define PADIDX(m) ((m) + ((m) >> 4))

// ---------------- GEMM v3 (unchanged): 32x128 tiles, grid 256 ----------------
__global__ __launch_bounds__(256)
void gemm_kv_kernel(const float* __restrict__ x,
                    const float* __restrict__ Wk,
                    const float* __restrict__ Wv,
                    float* __restrict__ K,
                    float* __restrict__ V,
                    float* __restrict__ partials)
{
    const int blk  = blockIdx.x;          // 0..255
    const int sel  = blk >> 7;            // 0 -> K, 1 -> V
    const int tid  = blk & 127;
    const int row0 = (tid >> 2) * 32;     // 32 row-tiles
    const int col0 = (tid & 3) * 128;     // 4 col-tiles
    const int t    = threadIdx.x;
    const int tc   = t & 31;
    const int tr   = t >> 5;              // 0..7
    const float* __restrict__ W   = sel ? Wv : Wk;
    float* __restrict__       Out = sel ? V  : K;

    __shared__ float xs[2][32][33];       // [buf][row][k], pad 33
    __shared__ float ws[2][32][128];      // [buf][k][col]
    __shared__ float red[4];

    float acc[4][4] = {{0,0,0,0},{0,0,0,0},{0,0,0,0},{0,0,0,0}};
    float  xr[4];
    float4 wv4[4];

    #define LD_GLOBAL(kb)                                                      \
        {   _Pragma("unroll")                                                  \
            for (int j = 0; j < 4; ++j) {                                      \
                const int idx = t + j * 256;                                   \
                xr[j] = x[(size_t)(row0 + (idx >> 5)) * DIMX + (kb) + (idx & 31)]; \
            }                                                                  \
            _Pragma("unroll")                                                  \
            for (int j = 0; j < 4; ++j) {                                      \
                const int f4 = t + j * 256;                                    \
                const int kk = f4 >> 5, cp = (f4 & 31) * 4;                    \
                wv4[j] = *(const float4*)&W[(size_t)((kb) + kk) * DIMX + col0 + cp]; \
            } }

    #define ST_LDS(buf)                                                        \
        {   _Pragma("unroll")                                                  \
            for (int j = 0; j < 4; ++j) {                                      \
                const int idx = t + j * 256;                                   \
                xs[buf][idx >> 5][idx & 31] = xr[j];                           \
            }                                                                  \
            _Pragma("unroll")                                                  \
            for (int j = 0; j < 4; ++j) {                                      \
                const int f4 = t + j * 256;                                    \
                const int kk = f4 >> 5, cp = (f4 & 31) * 4;                    \
                *(float4*)&ws[buf][kk][cp] = wv4[j];                           \
            } }

    LD_GLOBAL(0)
    ST_LDS(0)
    __syncthreads();

    for (int kb = 0; kb < 16; ++kb) {
        const int cur = kb & 1;
        if (kb < 15) LD_GLOBAL((kb + 1) * 32)
        #pragma unroll
        for (int kk = 0; kk < 32; ++kk) {
            const float4 w4 = *(const float4*)&ws[cur][kk][tc * 4];
            float xv[4];
            #pragma unroll
            for (int i = 0; i < 4; ++i) xv[i] = xs[cur][tr * 4 + i][kk];
            #pragma unroll
            for (int i = 0; i < 4; ++i) {
                acc[i][0] = fmaf(xv[i], w4.x, acc[i][0]);
                acc[i][1] = fmaf(xv[i], w4.y, acc[i][1]);
                acc[i][2] = fmaf(xv[i], w4.z, acc[i][2]);
                acc[i][3] = fmaf(xv[i], w4.w, acc[i][3]);
            }
        }
        if (kb < 15) {
            __syncthreads();
            ST_LDS(1 - cur)
            __syncthreads();
        }
    }

    float ss = 0.f;
    #pragma unroll
    for (int i = 0; i < 4; ++i) {
        const int row = row0 + tr * 4 + i;
        const float4 o = make_float4(acc[i][0], acc[i][1], acc[i][2], acc[i][3]);
        *(float4*)&Out[(size_t)row * DIMX + col0 + tc * 4] = o;
        ss += o.x * o.x + o.y * o.y + o.z * o.z + o.w * o.w;
    }
    if (sel == 0) {
        #pragma unroll
        for (int off = 32; off > 0; off >>= 1)
            ss += __shfl_down(ss, off, 64);
        if ((t & 63) == 0) red[t >> 6] = ss;
        __syncthreads();
        if (t == 0) partials[blk] = red[0] + red[1] + red[2] + red[3];
    } else {
        if (t == 0) partials[blk] = 0.f;
    }
    #undef LD_GLOBAL
    #undef ST_LDS
}

// 8-point DFT twiddles: exp(-2*pi*i*k/8)
__device__ __constant__ float C8[8] = {
    1.f, 0.70710678118654752440f, 0.f, -0.70710678118654752440f,
   -1.f, -0.70710678118654752440f, 0.f, 0.70710678118654752440f };
__device__ __constant__ float S8[8] = {
    0.f, -0.70710678118654752440f, -1.f, -0.70710678118654752440f,
    0.f,  0.70710678118654752440f,  1.f,  0.70710678118654752440f };

// elu(K/norm), S_k, P = S_k*V, 2x8 (b,h)-DFT. Writes [be][m][z], float4.
__global__ __launch_bounds__(256)
void stage1_kernel(const float* __restrict__ K,
                   const float* __restrict__ V,
                   const float* __restrict__ partials,
                   float2* __restrict__ Gk,
                   float2* __restrict__ Gp)
{
    const int m = blockIdx.x;     // 0..511
    const int t = threadIdx.x;
    __shared__ float kk[2][8][64];
    __shared__ float pp[2][8][64];
    __shared__ float skp[16][4];
    __shared__ float sk[2][8];
    __shared__ float sred[4];

    // reduce the 256 gemm partials -> global Frobenius scale
    float p = partials[t];
    #pragma unroll
    for (int off = 32; off > 0; off >>= 1)
        p += __shfl_down(p, off, 64);
    if ((t & 63) == 0) sred[t >> 6] = p;
    __syncthreads();
    const float scale = (float)(1.0 / sqrt((double)sred[0] + (double)sred[1] +
                                           (double)sred[2] + (double)sred[3]));

    for (int e = t; e < 1024; e += 256) {
        const int b = e >> 9, rem = e & 511, h = rem >> 6, z = rem & 63;
        const size_t src = (size_t)(b * 512 + m) * DIMX + h * 64 + z;
        const float kv = K[src] * scale;
        kk[b][h][z] = kv > 0.f ? kv : expm1f(kv);
        pp[b][h][z] = V[src];
    }
    __syncthreads();
    if (t < 64) {               // sk[b][h] = sum_z elu(k): 4 threads per (b,h)
        const int bh = t >> 2, q = t & 3;
        float s = 0.f;
        #pragma unroll
        for (int zz = 0; zz < 16; ++zz) s += kk[bh >> 3][bh & 7][q * 16 + zz];
        skp[bh][q] = s;
    }
    __syncthreads();
    if (t < 16) sk[t >> 3][t & 7] = skp[t][0] + skp[t][1] + skp[t][2] + skp[t][3];
    __syncthreads();
    for (int e = t; e < 1024; e += 256) {
        const int b = e >> 9, rem = e & 511, h = rem >> 6, z = rem & 63;
        pp[b][h][z] *= sk[b][h];
    }
    __syncthreads();

    // 2x8 (b,h)-DFT; each thread computes a z-PAIR -> float4 stores.
    for (int e2 = t; e2 < 512; e2 += 256) {
        const int be = e2 >> 5;          // 0..15
        const int zp = e2 & 31;          // z pair index
        const int beta = be >> 3, eta = be & 7;
        float4 rk, rp;
        #pragma unroll
        for (int zz = 0; zz < 2; ++zz) {
            const int z = zp * 2 + zz;
            float gkr = 0.f, gki = 0.f, gpr = 0.f, gpi = 0.f;
            #pragma unroll
            for (int b = 0; b < 2; ++b) {
                const float sgn = (beta & b) ? -1.f : 1.f;
                #pragma unroll
                for (int h = 0; h < 8; ++h) {
                    const int ph = (eta * h) & 7;
                    const float cr = C8[ph], ci = S8[ph];
                    const float a = kk[b][h][z] * sgn;
                    gkr = fmaf(a, cr, gkr); gki = fmaf(a, ci, gki);
                    const float p2 = pp[b][h][z] * sgn;
                    gpr = fmaf(p2, cr, gpr); gpi = fmaf(p2, ci, gpi);
                }
            }
            if (zz == 0) { rk.x = gkr; rk.y = gki; rp.x = gpr; rp.y = gpi; }
            else         { rk.z = gkr; rk.w = gki; rp.z = gpr; rp.w = gpi; }
        }
        const size_t o = ((size_t)be * NPOS + m) * 64 + zp * 2;
        *(float4*)&Gk[o] = rk;
        *(float4*)&Gp[o] = rp;
    }
}

// ---------------- Zero-padded 1024-pt radix-2 DIF FFT + divide ----------------
// Swizzle: blk = be*32 + l*8 + j, zg = j*4 + l  ->  the 4 blocks sharing each
// 64B out-line / Gk-line (zg group of 4, fixed be) have equal blk%8 (same XCD).
__global__ __launch_bounds__(256)
void fft_div_kernel(const float2* __restrict__ Gk,   // [be][m][z]
                    const float2* __restrict__ Gp,
                    float* __restrict__ out, int out_cplx)
{
    const int blk = blockIdx.x;
    const int j  = blk & 7;
    const int l  = (blk >> 3) & 3;
    const int be = blk >> 5;
    const int zg = j * 4 + l;            // z = 2*zg, 2*zg+1
    const int t  = threadIdx.x;

    __shared__ float2 g[4][1088];   // arr = a*2+zi, padded 1024 -> 1088
    __shared__ float2 w[544];       // padded 512 twiddles

    for (int jj = t; jj < 512; jj += 256) {
        double s, cc;
        sincos(-6.2831853071795864769 * (double)jj / 1024.0, &s, &cc);
        w[PADIDX(jj)] = make_float2((float)cc, (float)s);
    }
    __syncthreads();

    // load z-pair as float4 + fused stage 0 (upper half of input is zero)
    for (int e = t; e < 1024; e += 256) {
        const int a = e >> 9;            // 0 -> Gk, 1 -> Gp
        const int m = e & 511;
        const float4 v4 = *(const float4*)&(a ? Gp : Gk)[((size_t)be * NPOS + m) * 64 + zg * 2];
        const float2 v0 = make_float2(v4.x, v4.y);
        const float2 v1 = make_float2(v4.z, v4.w);
        const float2 tw = w[PADIDX(m)];
        g[a * 2 + 0][PADIDX(m)] = v0;
        g[a * 2 + 1][PADIDX(m)] = v1;
        g[a * 2 + 0][PADIDX(m + 512)] = make_float2(v0.x * tw.x - v0.y * tw.y,
                                                    v0.x * tw.y + v0.y * tw.x);
        g[a * 2 + 1][PADIDX(m + 512)] = make_float2(v1.x * tw.x - v1.y * tw.y,
                                                    v1.x * tw.y + v1.y * tw.x);
    }
    __syncthreads();

    #pragma unroll
    for (int s = 1; s <= 9; ++s) {
        const int S = 512 >> s;
        const int lg = 9 - s;
        #pragma unroll
        for (int q = 0; q < 8; ++q) {
            const int B    = t + 256 * q;
            const int arr  = B >> 9;
            const int beta = B & 511;
            const int jb   = beta & (S - 1);
            const int seg  = beta >> lg;
            const int u    = (seg << (lg + 1)) + jb;
            const int v    = u + S;
            const float2 tw = w[PADIDX(jb << s)];
            const float2 A  = g[arr][PADIDX(u)];
            const float2 Bb = g[arr][PADIDX(v)];
            g[arr][PADIDX(u)] = make_float2(A.x + Bb.x, A.y + Bb.y);
            const float sr = A.x - Bb.x, si = A.y - Bb.y;
            g[arr][PADIDX(v)] = make_float2(sr * tw.x - si * tw.y,
                                            sr * tw.y + si * tw.x);
        }
        __syncthreads();
    }

    // even positions 2i hold mu = bitrev9(i). Divide both z and store float4.
    for (int e2 = t; e2 < 512; e2 += 256) {
        const int i  = e2;
        const int pi = PADIDX(2 * i);
        const int mu = (int)(__brev((unsigned)i) >> 23);   // bitrev9
        float4 res;
        #pragma unroll
        for (int zi = 0; zi < 2; ++zi) {
            const float2 D  = g[zi][pi];
            const float2 Nm = g[2 + zi][pi];
            const float inv = 1.f / (D.x * D.x + D.y * D.y);
            const float rr = (Nm.x * D.x + Nm.y * D.y) * inv;
            const float ri = (Nm.y * D.x - Nm.x * D.y) * inv;
            if (zi == 0) { res.x = rr; res.y = ri; }
            else         { res.z = rr; res.w = ri; }
        }
        const size_t o = ((size_t)be * NPOS + mu) * 64 + zg * 2;
        if (out_cplx) {
            *(float4*)&((float2*)out)[o] = res;
        } else {
            out[o]     = res.x;
            out[o + 1] = res.z;
        }
    }
}

// Fallback mdft (fp64, [be][m][z] layout) for the ws-aliasing path.
__global__ __launch_bounds__(256)
void mdft_fallback_kernel(const float2* __restrict__ Gk,
                          const float2* __restrict__ Gp,
                          float* __restrict__ out,
                          int out_cplx)
{
    const int blk = blockIdx.x;
    const int be = blk >> 6, z = blk & 63;
    const int t = threadIdx.x;
    __shared__ float2 gk[512];
    __shared__ float2 gp[512];
    __shared__ float2 w[1024];

    for (int m = t; m < 512; m += 256) {
        const size_t idx = ((size_t)be * NPOS + m) * 64 + z;
        gk[m] = Gk[idx];
        gp[m] = Gp[idx];
    }
    for (int jj = t; jj < 1024; jj += 256) {
        double s, c;
        sincos(-6.2831853071795864769 * (double)jj / 1024.0, &s, &c);
        w[jj] = make_float2((float)c, (float)s);
    }
    __syncthreads();

    #pragma unroll
    for (int half = 0; half < 2; ++half) {
        const int mu = t + half * 256;
        double dr = 0.0, di = 0.0, nr = 0.0, ni = 0.0;
        int idx = 0;
        for (int m = 0; m < 512; ++m) {
            const float2 tw = w[idx];
            idx = (idx + mu) & 1023;
            const float2 a = gk[m];
            dr += (double)(a.x * tw.x - a.y * tw.y);
            di += (double)(a.x * tw.y + a.y * tw.x);
            const float2 p = gp[m];
            nr += (double)(p.x * tw.x - p.y * tw.y);
            ni += (double)(p.x * tw.y + p.y * tw.x);
        }
        const double dmag = dr * dr + di * di;
        const double orr = (nr * dr + ni * di) / dmag;
        const double oii = (ni * dr - nr * di) / dmag;
        const size_t o = ((size_t)be * NPOS + mu) * 64 + z;
        if (out_cplx) {
            out[2 * o]     = (float)orr;
            out[2 * o + 1] = (float)oii;
        } else {
            out[o] = (float)orr;
        }
    }
}

extern "C" void kernel_launch(void* const* d_in, const int* in_sizes, int n_in,
                              void* d_out, int out_size, void* d_ws, size_t ws_size,
                              hipStream_t stream)
{
    // inputs: x, Wq, Wk, Wv, Er — only x, Wk, Wv needed
    const float* x  = (const float*)d_in[0];
    const float* Wk = (const float*)d_in[2];
    const float* Wv = (const float*)d_in[3];
    float* out = (float*)d_out;

    char* ws = (char*)d_ws;
    float*  K    = (float*)(ws);                           // 2 MB
    float*  V    = (float*)(ws + (size_t)2097152);         // 2 MB
    float2* Gk   = (float2*)(ws + (size_t)4194304);        // 4 MB
    float*  part = (float*)(ws + (size_t)8388608);         // 1 KB (256 floats)
    const int out_cplx = (out_size >= 2 * 2 * 8 * 512 * 64) ? 1 : 0;

    const bool ws_big = (ws_size >= (size_t)8390656 + (size_t)4194304);
    float2* Gp = ws_big ? (float2*)(ws + (size_t)8390656)  // 4 MB
                        : (float2*)d_out;                  // alias-safe fallback

    hipLaunchKernelGGL(gemm_kv_kernel, dim3(256), dim3(256), 0, stream,
                       x, Wk, Wv, K, V, part);
    hipLaunchKernelGGL(stage1_kernel, dim3(512), dim3(256), 0, stream,
                       K, V, part, Gk, Gp);
    if (ws_big) {
        hipLaunchKernelGGL(fft_div_kernel, dim3(512), dim3(256), 0, stream,
                           Gk, Gp, out, out_cplx);
    } else {
        hipLaunchKernelGGL(mdft_fallback_kernel, dim3(1024), dim3(256), 0, stream,
                           Gk, Gp, out, out_cplx);
    }
}